// Round 2
// baseline (196.811 us; speedup 1.0000x reference)
//
#include <hip/hip_runtime.h>
#include <math.h>

// Density loss: B=8, N=2048, C=3, K=16 (self-distance 0 included).
// Kernel 1: wave handles 2 points, sharing LDS candidate reads.
//   thr = 16th smallest of 32 pair-mins (valid upper bound on v16, E[cnt]~21).
//   Each lane shift-inserts its <=3 qualifiers into registers; sum16 =
//   total qualifier sum - (cnt-16) largest, extracted via max-butterfly rounds.
//   Exact per-wave fallback if any lane >3 qualifiers or cnt>48 (~1%).
// Kernel 2: single block reduces 2x8x2048 per-point sums -> scalar MSE.

#define NPTS 2048

// Sort 32 pair-duplicated lane values (pair-min of lane pairs), return
// logical element 15 = 16th smallest. Runs two independent sorts (A,B)
// interleaved so the serial swizzle chains overlap.
__device__ __forceinline__ void thr16x2(float a, float b, int lane,
                                        float* thrA, float* thrB) {
  float va = fminf(a, __shfl_xor(a, 1));
  float vb = fminf(b, __shfl_xor(b, 1));
  const int p = lane >> 1;  // logical index in [0,32)
  #pragma unroll
  for (int k = 2; k <= 32; k <<= 1) {
    #pragma unroll
    for (int j = k >> 1; j > 0; j >>= 1) {
      float oa = __shfl_xor(va, j << 1);
      float ob = __shfl_xor(vb, j << 1);
      bool desc = (p & k) != 0;
      bool lower = (p & j) == 0;
      va = (lower != desc) ? fminf(va, oa) : fmaxf(va, oa);
      vb = (lower != desc) ? fminf(vb, ob) : fmaxf(vb, ob);
    }
  }
  *thrA = __shfl(va, 30);  // logical 15 lives at lanes {30,31}
  *thrB = __shfl(vb, 30);
}

// Exact fallback: 16 rounds of global min-extraction over register-held d[32].
__device__ __forceinline__ float exact16(const float* d, int lane) {
  unsigned consumed = 0u;
  float s = 0.f;
  for (int r = 0; r < 16; ++r) {
    float bv = INFINITY;
    int bi = 0;
    #pragma unroll
    for (int m = 0; m < 32; ++m) {
      bool ok = (((consumed >> m) & 1u) == 0u) && (d[m] < bv);
      bv = ok ? d[m] : bv;
      bi = ok ? m : bi;
    }
    int bl = lane;
    #pragma unroll
    for (int ofs = 1; ofs < 64; ofs <<= 1) {
      float ov = __shfl_xor(bv, ofs);
      int ol = __shfl_xor(bl, ofs);
      bool take = (ov < bv) || (ov == bv && ol < bl);
      bv = take ? ov : bv;
      bl = take ? ol : bl;
    }
    s += bv;
    if (lane == bl) consumed |= (1u << bi);
  }
  return s;
}

// Remove the (cnt-16) largest qualifiers from the slot multiset; return sum16.
__device__ __forceinline__ float finish(float w0, float w1, float w2,
                                        int cnt, float sq, int lane) {
  const int r = cnt - 16;  // wave-uniform
  for (int q = 0; q < r; ++q) {
    float lmax = fmaxf(w0, fmaxf(w1, w2));
    float bv = lmax;
    #pragma unroll
    for (int ofs = 1; ofs < 64; ofs <<= 1) bv = fmaxf(bv, __shfl_xor(bv, ofs));
    unsigned long long msk = __ballot(lmax == bv);
    int bl = __builtin_ctzll(msk);
    sq -= bv;
    bool me = (lane == bl);
    bool k0 = me && (w0 == bv);
    bool k1 = me && !k0 && (w1 == bv);
    bool k2 = me && !k0 && !k1;
    w0 = k0 ? -INFINITY : w0;
    w1 = k1 ? -INFINITY : w1;
    w2 = k2 ? -INFINITY : w2;
  }
  return sq;
}

__global__ __launch_bounds__(256, 4) void knn_sum16_kernel(
    const float* __restrict__ seed, const float* __restrict__ gt,
    float* __restrict__ out_sums) {
  __shared__ float4 pts[NPTS];  // 32 KB

  const int bid = blockIdx.x;   // 4096 = 2*8*256
  const int t = bid >> 11;      // tensor
  const int b = (bid >> 8) & 7; // batch
  const int g = bid & 255;      // group of 8 points
  const float* base = (t == 0 ? seed : gt) + b * (NPTS * 3);
  const int tid = threadIdx.x;

  // Stage 2048 points: 8 points (24 floats = 6 float4) per thread.
  {
    const float4* src = (const float4*)base + tid * 6;
    float4 q0 = src[0], q1 = src[1], q2 = src[2];
    float4 q3 = src[3], q4 = src[4], q5 = src[5];
    float f[24] = {q0.x, q0.y, q0.z, q0.w, q1.x, q1.y, q1.z, q1.w,
                   q2.x, q2.y, q2.z, q2.w, q3.x, q3.y, q3.z, q3.w,
                   q4.x, q4.y, q4.z, q4.w, q5.x, q5.y, q5.z, q5.w};
    int p = tid * 8;
    #pragma unroll
    for (int j = 0; j < 8; ++j)
      pts[p + j] = make_float4(f[3 * j], f[3 * j + 1], f[3 * j + 2], 0.f);
  }
  __syncthreads();

  const int wave = tid >> 6, lane = tid & 63;
  const int iA = g * 8 + wave, iB = iA + 4;
  const float4 pA = pts[iA], pB = pts[iB];

  // 32 candidates per lane, shared between the two points.
  float dA[32], dB[32];
  float mnA = INFINITY, mnB = INFINITY;
  #pragma unroll
  for (int m = 0; m < 32; ++m) {
    float4 c = pts[lane + (m << 6)];
    float ax = pA.x - c.x, ay = pA.y - c.y, az = pA.z - c.z;
    float bx = pB.x - c.x, by = pB.y - c.y, bz = pB.z - c.z;
    float da = fmaf(az, az, fmaf(ay, ay, ax * ax));
    float db = fmaf(bz, bz, fmaf(by, by, bx * bx));
    dA[m] = da;
    dB[m] = db;
    mnA = fminf(mnA, da);
    mnB = fminf(mnB, db);
  }

  float thrA, thrB;
  thr16x2(mnA, mnB, lane, &thrA, &thrB);

  // Branchless shift-insert of qualifiers (<=3 tracked per lane) + count.
  float w0A = 0.f, w1A = 0.f, w2A = 0.f, w0B = 0.f, w1B = 0.f, w2B = 0.f;
  int cA = 0, cB = 0;
  #pragma unroll
  for (int m = 0; m < 32; ++m) {
    bool tA = dA[m] <= thrA;
    w2A = tA ? w1A : w2A;
    w1A = tA ? w0A : w1A;
    w0A = tA ? dA[m] : w0A;
    cA += tA ? 1 : 0;
    bool tB = dB[m] <= thrB;
    w2B = tB ? w1B : w2B;
    w1B = tB ? w0B : w1B;
    w0B = tB ? dB[m] : w0B;
    cB += tB ? 1 : 0;
  }

  unsigned long long badA = __ballot(cA > 3);
  unsigned long long badB = __ballot(cB > 3);

  // Butterfly-reduce counts and qualifier sums (slots hold all qualifiers
  // when no lane overflowed; zero-init slots add 0 to the sum).
  int cntA = cA, cntB = cB;
  float sqA = w0A + w1A + w2A, sqB = w0B + w1B + w2B;
  #pragma unroll
  for (int ofs = 1; ofs < 64; ofs <<= 1) {
    cntA += __shfl_xor(cntA, ofs);
    cntB += __shfl_xor(cntB, ofs);
    sqA += __shfl_xor(sqA, ofs);
    sqB += __shfl_xor(sqB, ofs);
  }

  float outA, outB;
  if (badA == 0ull && cntA <= 48)
    outA = finish(w0A, w1A, w2A, cntA, sqA, lane);
  else
    outA = exact16(dA, lane);
  if (badB == 0ull && cntB <= 48)
    outB = finish(w0B, w1B, w2B, cntB, sqB, lane);
  else
    outB = exact16(dB, lane);

  if (lane == 0) {
    out_sums[bid * 8 + wave] = outA;
    out_sums[bid * 8 + 4 + wave] = outB;
  }
}

__global__ __launch_bounds__(1024) void final_reduce_kernel(
    const float* __restrict__ sums, float* __restrict__ out) {
  __shared__ float partial[16];
  const int tid = threadIdx.x;
  const int wave = tid >> 6;
  const int lane = tid & 63;
  float s = 0.f;
  #pragma unroll
  for (int m = 0; m < 32; ++m) s += sums[wave * 2048 + lane + (m << 6)];
  #pragma unroll
  for (int ofs = 32; ofs >= 1; ofs >>= 1) s += __shfl_xor(s, ofs);
  if (lane == 0) partial[wave] = s;
  __syncthreads();
  if (tid == 0) {
    const float scale = 1.f / (2048.f * 16.f);
    float acc = 0.f;
    #pragma unroll
    for (int bb = 0; bb < 8; ++bb) {
      float diff = (partial[bb] - partial[8 + bb]) * scale;
      acc += diff * diff;
    }
    out[0] = acc * 0.125f;
  }
}

extern "C" void kernel_launch(void* const* d_in, const int* in_sizes, int n_in,
                              void* d_out, int out_size, void* d_ws, size_t ws_size,
                              hipStream_t stream) {
  const float* seed = (const float*)d_in[0];
  const float* gt = (const float*)d_in[1];
  float* out = (float*)d_out;
  float* ws = (float*)d_ws;  // 32768 floats = 128 KB

  knn_sum16_kernel<<<4096, 256, 0, stream>>>(seed, gt, ws);
  final_reduce_kernel<<<1, 1024, 0, stream>>>(ws, out);
}

// Round 3
// 143.815 us; speedup vs baseline: 1.3685x; 1.3685x over previous
//
#include <hip/hip_runtime.h>
#include <math.h>

// Density loss: B=8, N=2048, C=3, K=16 (self-distance 0 included).
// Kernel 1: 1024-thread blocks, 16 waves, each wave handles 4 points sharing
//   the 32 ds_read_b128 candidate reads. Per lane, per point: sorted 5-slot
//   running min-list (registers only; no spillable arrays). Threshold =
//   16th-smallest lane-min (bitonic64, interleaved x4). If no lane overflowed
//   (s4 <= thr), slots hold the full qualifier multiset: sum16 = sum of
//   qualifiers minus the (cnt-16) largest (max-butterfly rounds, E~3).
//   Rare overflow (P~1e-3/point) -> exact streaming extraction over LDS.
//   Block writes ONE partial sum (sum of its 64 point-sums).
// Kernel 2: 1 block reduces 512 partials -> scalar MSE.

#define NPTS 2048

// Exact fallback: 16 rounds of global min-extraction with lexicographic
// (value, candidate-index) keys; re-reads LDS each round. No local arrays.
__device__ __attribute__((noinline)) float exact_stream(
    const float4* __restrict__ pts, float px, float py, float pz, int lane) {
  float lastV = -INFINITY;
  int lastI = -1;
  float s = 0.f;
  for (int r = 0; r < 16; ++r) {
    float bv = INFINITY;
    int bi = 0x7fffffff;
    #pragma unroll
    for (int m = 0; m < 32; ++m) {
      float4 c = pts[lane + (m << 6)];
      float dx = px - c.x, dy = py - c.y, dz = pz - c.z;
      float d = fmaf(dz, dz, fmaf(dy, dy, dx * dx));
      int idx = (m << 6) | lane;
      bool gt = (d > lastV) || (d == lastV && idx > lastI);
      bool better = gt && ((d < bv) || (d == bv && idx < bi));
      bv = better ? d : bv;
      bi = better ? idx : bi;
    }
    #pragma unroll
    for (int ofs = 1; ofs < 64; ofs <<= 1) {
      float ov = __shfl_xor(bv, ofs);
      int oi = __shfl_xor(bi, ofs);
      bool take = (ov < bv) || (ov == bv && oi < bi);
      bv = take ? ov : bv;
      bi = take ? oi : bi;
    }
    s += bv;
    lastV = bv;
    lastI = bi;
  }
  return s;
}

__global__ __launch_bounds__(1024) void knn_kernel(
    const float* __restrict__ seed, const float* __restrict__ gt,
    float* __restrict__ out_partial) {
  __shared__ float4 pts[NPTS];  // 32 KB
  __shared__ float wsum[16];

  const int bid = blockIdx.x;    // 512 = 2*8*32
  const int t = bid >> 8;        // tensor
  const int b = (bid >> 5) & 7;  // batch
  const int g = bid & 31;        // group of 64 points
  const float* base = (t == 0 ? seed : gt) + b * (NPTS * 3);
  const int tid = threadIdx.x;

  // Stage 2048 points; consecutive b128 writes (conflict-free, R1-proven).
  #pragma unroll
  for (int r = 0; r < 2; ++r) {
    int p = tid + (r << 10);
    pts[p] = make_float4(base[3 * p], base[3 * p + 1], base[3 * p + 2], 0.f);
  }
  __syncthreads();

  const int wave = tid >> 6, lane = tid & 63;
  const int i0 = (g << 6) + (wave << 2);

  float px[4], py[4], pz[4];
  #pragma unroll
  for (int j = 0; j < 4; ++j) {
    float4 q = pts[i0 + j];
    px[j] = q.x; py[j] = q.y; pz[j] = q.z;
  }

  // Sorted 5 smallest per lane per point (ascending s0..s4).
  float s0[4], s1[4], s2[4], s3[4], s4[4];
  #pragma unroll
  for (int j = 0; j < 4; ++j) {
    s0[j] = s1[j] = s2[j] = s3[j] = s4[j] = INFINITY;
  }

  #pragma unroll 8
  for (int m = 0; m < 32; ++m) {
    float4 c = pts[lane + (m << 6)];
    #pragma unroll
    for (int j = 0; j < 4; ++j) {
      float dx = px[j] - c.x, dy = py[j] - c.y, dz = pz[j] - c.z;
      float d = fmaf(dz, dz, fmaf(dy, dy, dx * dx));
      float u;
      u = fminf(s0[j], d); d = fmaxf(s0[j], d); s0[j] = u;
      u = fminf(s1[j], d); d = fmaxf(s1[j], d); s1[j] = u;
      u = fminf(s2[j], d); d = fmaxf(s2[j], d); s2[j] = u;
      u = fminf(s3[j], d); d = fmaxf(s3[j], d); s3[j] = u;
      s4[j] = fminf(s4[j], d);
    }
  }

  // thr[j] = 16th smallest lane-min: interleaved bitonic64 over s0.
  float v0 = s0[0], v1 = s0[1], v2 = s0[2], v3 = s0[3];
  #pragma unroll
  for (int k = 2; k <= 64; k <<= 1) {
    #pragma unroll
    for (int j = k >> 1; j > 0; j >>= 1) {
      bool keepmin = ((lane & j) == 0) != ((lane & k) != 0);
      float p0 = __shfl_xor(v0, j), p1 = __shfl_xor(v1, j);
      float p2 = __shfl_xor(v2, j), p3 = __shfl_xor(v3, j);
      v0 = keepmin ? fminf(v0, p0) : fmaxf(v0, p0);
      v1 = keepmin ? fminf(v1, p1) : fmaxf(v1, p1);
      v2 = keepmin ? fminf(v2, p2) : fmaxf(v2, p2);
      v3 = keepmin ? fminf(v3, p3) : fmaxf(v3, p3);
    }
  }
  float thr[4] = {__shfl(v0, 15), __shfl(v1, 15), __shfl(v2, 15),
                  __shfl(v3, 15)};

  // Per-lane qualifier count + sum; conservative overflow flag.
  float cnt[4], sq[4];
  unsigned long long badm[4];
  #pragma unroll
  for (int j = 0; j < 4; ++j) {
    float c = 0.f, q = 0.f;
    bool q0 = s0[j] <= thr[j]; c += q0 ? 1.f : 0.f; q += q0 ? s0[j] : 0.f;
    bool q1 = s1[j] <= thr[j]; c += q1 ? 1.f : 0.f; q += q1 ? s1[j] : 0.f;
    bool q2 = s2[j] <= thr[j]; c += q2 ? 1.f : 0.f; q += q2 ? s2[j] : 0.f;
    bool q3 = s3[j] <= thr[j]; c += q3 ? 1.f : 0.f; q += q3 ? s3[j] : 0.f;
    bool q4 = s4[j] <= thr[j]; c += q4 ? 1.f : 0.f; q += q4 ? s4[j] : 0.f;
    cnt[j] = c; sq[j] = q;
    badm[j] = __ballot(q4);  // lane may have dropped a qualifier
  }
  #pragma unroll
  for (int ofs = 1; ofs < 64; ofs <<= 1) {
    #pragma unroll
    for (int j = 0; j < 4; ++j) {
      cnt[j] += __shfl_xor(cnt[j], ofs);
      sq[j] += __shfl_xor(sq[j], ofs);
    }
  }

  float out[4];
  #pragma unroll
  for (int j = 0; j < 4; ++j) {
    if (badm[j] != 0ull) {  // wave-uniform, rare (~1e-3/point)
      out[j] = exact_stream(pts, px[j], py[j], pz[j], lane);
    } else {
      float a0 = s0[j], a1 = s1[j], a2 = s2[j], a3 = s3[j], a4 = s4[j];
      const float T = thr[j];
      float S = sq[j];
      const int r = (int)cnt[j] - 16;  // wave-uniform, >= 0
      for (int q = 0; q < r; ++q) {
        float lm = -INFINITY;
        lm = (a0 <= T) ? fmaxf(lm, a0) : lm;
        lm = (a1 <= T) ? fmaxf(lm, a1) : lm;
        lm = (a2 <= T) ? fmaxf(lm, a2) : lm;
        lm = (a3 <= T) ? fmaxf(lm, a3) : lm;
        lm = (a4 <= T) ? fmaxf(lm, a4) : lm;
        float bv = lm;
        #pragma unroll
        for (int ofs = 1; ofs < 64; ofs <<= 1) bv = fmaxf(bv, __shfl_xor(bv, ofs));
        S -= bv;
        int owner = __builtin_ctzll(__ballot(lm == bv));
        if (lane == owner) {  // retire one instance (INF leaves qualifier set)
          if (a0 == bv) a0 = INFINITY;
          else if (a1 == bv) a1 = INFINITY;
          else if (a2 == bv) a2 = INFINITY;
          else if (a3 == bv) a3 = INFINITY;
          else a4 = INFINITY;
        }
      }
      out[j] = S;
    }
  }

  // Block-level partial: sum of this block's 64 point-sums.
  float wtot = out[0] + out[1] + out[2] + out[3];  // uniform across lanes
  if (lane == 0) wsum[wave] = wtot;
  __syncthreads();
  if (wave == 0) {
    float v = (lane < 16) ? wsum[lane] : 0.f;
    #pragma unroll
    for (int ofs = 1; ofs < 64; ofs <<= 1) v += __shfl_xor(v, ofs);
    if (lane == 0) out_partial[bid] = v;
  }
}

__global__ __launch_bounds__(512) void final_kernel(
    const float* __restrict__ part, float* __restrict__ out) {
  __shared__ float acc[16];
  const int tid = threadIdx.x;  // 512
  const int lane = tid & 63;
  float v = part[tid];
  // Sum within aligned 32-lane groups (one (tensor,batch) segment each).
  #pragma unroll
  for (int ofs = 1; ofs < 32; ofs <<= 1) v += __shfl_xor(v, ofs);
  if ((lane & 31) == 0) acc[tid >> 5] = v;
  __syncthreads();
  if (tid == 0) {
    const float scale = 1.f / (2048.f * 16.f);
    float a = 0.f;
    #pragma unroll
    for (int bb = 0; bb < 8; ++bb) {
      float diff = (acc[bb] - acc[8 + bb]) * scale;
      a += diff * diff;
    }
    out[0] = a * 0.125f;
  }
}

extern "C" void kernel_launch(void* const* d_in, const int* in_sizes, int n_in,
                              void* d_out, int out_size, void* d_ws, size_t ws_size,
                              hipStream_t stream) {
  const float* seed = (const float*)d_in[0];
  const float* gt = (const float*)d_in[1];
  float* out = (float*)d_out;
  float* ws = (float*)d_ws;  // 512 floats used

  knn_kernel<<<512, 1024, 0, stream>>>(seed, gt, ws);
  final_kernel<<<1, 512, 0, stream>>>(ws, out);
}